// Round 6
// baseline (567.976 us; speedup 1.0000x reference)
//
#include <hip/hip_runtime.h>
#include <stdint.h>

#define D_MODEL 1024
#define NHEAD 16
#define DH 64
#define DFF 4096
#define BATCH 4
#define SEQ 2048
#define MTOT (BATCH*SEQ)   // 8192 rows total

// Q pre-scale folds 1/sqrt(Dh) AND log2(e) so softmax uses raw v_exp_f32 (exp2):
//   s' = s * log2e;  clip upper bound 10*log2e;  p = exp2(min(s',10*log2e)) = exp(min(s,10))
#define QSCALE 0.18033688011112043f   // 0.125 * log2(e)
#define CLIP2  14.426950408889634f    // 10 * log2(e)

typedef short short8 __attribute__((ext_vector_type(8)));
typedef float f32x4 __attribute__((ext_vector_type(4)));
typedef unsigned int uint;

#if __has_builtin(__builtin_amdgcn_exp2f)
#define EXP2(x) __builtin_amdgcn_exp2f(x)
#else
#define EXP2(x) __expf((x) * 0.6931471805599453f)
#endif

__device__ inline unsigned short f2bf(float f) {
  union { float f; unsigned u; } v; v.f = f;
  unsigned r = v.u + 0x7fffu + ((v.u >> 16) & 1u);
  return (unsigned short)(r >> 16);
}
__device__ inline float bf2f(unsigned short b) {
  union { unsigned u; float f; } v; v.u = ((unsigned)b) << 16;
  return v.f;
}
// truncation-pack two non-negative floats to bf16 pair in one dword: [lo | hi<<16]
__device__ inline unsigned pack_trunc(float lo, float hi) {
  union { float f; unsigned u; } a, b; a.f = lo; b.f = hi;
  return __builtin_amdgcn_perm(b.u, a.u, 0x07060302u);
}
// async 16B global -> LDS (wave-uniform base + lane*16 contract)
__device__ __forceinline__ void async16(const unsigned short* g, unsigned short* l) {
  __builtin_amdgcn_global_load_lds(
      (const __attribute__((address_space(1))) unsigned int*)g,
      (__attribute__((address_space(3))) unsigned int*)l, 16, 0, 0);
}

// ---------------- cast x -> bf16 ----------------
__global__ void cast_kernel(const float* __restrict__ in, unsigned short* __restrict__ out, int n4) {
  int i = blockIdx.x * blockDim.x + threadIdx.x;
  if (i < n4) {
    float4 v = ((const float4*)in)[i];
    ushort4 o;
    o.x = f2bf(v.x); o.y = f2bf(v.y); o.z = f2bf(v.z); o.w = f2bf(v.w);
    ((ushort4*)out)[i] = o;
  }
}

// ------------- ALL weight transposes in ONE launch (z-switched) -------------
// in [K][N] f32 -> out [N][K] bf16 (optionally scaled)
__global__ void transpose_weights_kernel(
    const float* __restrict__ wq, const float* __restrict__ wk,
    const float* __restrict__ wv, const float* __restrict__ wo,
    const float* __restrict__ w1, const float* __restrict__ w2,
    unsigned short* __restrict__ wqkvT, unsigned short* __restrict__ woT,
    unsigned short* __restrict__ w1T, unsigned short* __restrict__ w2T) {
  __shared__ unsigned short tile[32][33];
  const float* in; unsigned short* out; int K, N; float scale = 1.0f;
  switch (blockIdx.z) {
    case 0:  in = wq; out = wqkvT;           K = 1024; N = 1024; scale = QSCALE; break;
    case 1:  in = wk; out = wqkvT + 1048576; K = 1024; N = 1024; break;
    case 2:  in = wv; out = wqkvT + 2097152; K = 1024; N = 1024; break;
    case 3:  in = wo; out = woT;             K = 1024; N = 1024; break;
    case 4:  in = w1; out = w1T;             K = 1024; N = 4096; break;
    default: in = w2; out = w2T;             K = 4096; N = 1024; break;
  }
  int n0 = blockIdx.x * 32, k0 = blockIdx.y * 32;
  if (n0 >= N || k0 >= K) return;
  int tx = threadIdx.x & 31, ty = threadIdx.x >> 5;  // 32 x 8
#pragma unroll
  for (int j = 0; j < 32; j += 8)
    tile[ty + j][tx] = f2bf(in[(size_t)(k0 + ty + j) * N + n0 + tx] * scale);
  __syncthreads();
#pragma unroll
  for (int j = 0; j < 32; j += 8)
    out[(size_t)(n0 + ty + j) * K + k0 + tx] = tile[tx][ty + j];
}

// ------------- concat + scale biases into [3072] -------------
__global__ void bias_concat_kernel(const float* __restrict__ bq, const float* __restrict__ bk,
                                   const float* __restrict__ bv, float* __restrict__ o) {
  int i = blockIdx.x * 256 + threadIdx.x;
  if (i < 3 * D_MODEL) {
    float v = (i < D_MODEL) ? bq[i] * QSCALE
            : (i < 2 * D_MODEL) ? bk[i - D_MODEL] : bv[i - 2 * D_MODEL];
    o[i] = v;
  }
}

// ------------- transpose V (from qkv cols 2048..3071) into Vt_g[bh][dh][kv] -------------
__global__ void transpose_v_kernel(const unsigned short* __restrict__ QKV,
                                   unsigned short* __restrict__ Vt) {
  __shared__ unsigned short tile[32][33];
  int bh = blockIdx.z, b = bh >> 4, h = bh & 15;
  int kv0 = blockIdx.x * 32, dh0 = blockIdx.y * 32;
  int tx = threadIdx.x & 31, ty = threadIdx.x >> 5;  // 32 x 8
#pragma unroll
  for (int j = 0; j < 32; j += 8)
    tile[ty + j][tx] = QKV[(size_t)(b * SEQ + kv0 + ty + j) * 3072 + 2048 + h * DH + dh0 + tx];
  __syncthreads();
#pragma unroll
  for (int j = 0; j < 32; j += 8)
    Vt[(size_t)(bh * DH + dh0 + ty + j) * SEQ + kv0 + tx] = tile[tx][ty + j];
}

// ------------- GEMM: C[M][N] = A[M][K] * Bt[N][K]^T + bias (m97-style async staging) -------------
// 1D grid, XCD-compact swizzle: xcd = blockIdx.x&7 owns a contiguous band of 8 m-tiles
// (1024 rows) x all n-tiles, ordered n-fast.
template<int RELU, int OUT_BF16>
__global__ __launch_bounds__(256, 2) void gemm_bt_kernel(
    const unsigned short* __restrict__ A,
    const unsigned short* __restrict__ Bt,
    const float* __restrict__ bias,
    void* __restrict__ Cout,
    int M, int N, int K) {
  __shared__ __align__(16) unsigned short As[128][32];
  __shared__ __align__(16) unsigned short Bs[128][32];
  const int GX = N >> 7;                    // n-tiles
  const int xcd = blockIdx.x & 7;
  const int li = blockIdx.x >> 3;           // 0 .. 8*GX-1
  const int im = xcd * 8 + li / GX;         // m-tile (8 per XCD band, M=8192 always)
  const int in_ = li % GX;                  // n-tile, fast-varying within band
  const int m0 = im * 128, n0 = in_ * 128;
  const int tid = threadIdx.x;
  const int wave = tid >> 6, lane = tid & 63;
  const int wm = (wave >> 1) * 64, wn = (wave & 1) * 64;
  const int lm = lane & 15, lq = lane >> 4, lk = (lane >> 4) * 8;
  const int sr = tid >> 2;          // staging row 0..63 (+64 on 2nd round)
  const int sc = (tid & 3) * 8;     // staging col {0,8,16,24}
  f32x4 acc[4][4] = {};

  for (int k0 = 0; k0 < K; k0 += 32) {
    __syncthreads();
#pragma unroll
    for (int s = 0; s < 2; s++) {
      int row = sr + s * 64;
      async16(A  + (size_t)(m0 + row) * K + k0 + sc, &As[0][0] + row * 32 + sc);
      async16(Bt + (size_t)(n0 + row) * K + k0 + sc, &Bs[0][0] + row * 32 + sc);
    }
    __syncthreads();
    short8 af[4], bfr[4];
#pragma unroll
    for (int t = 0; t < 4; t++) {
      af[t]  = *(const short8*)(&As[wm + t * 16 + lm][lk]);
      bfr[t] = *(const short8*)(&Bs[wn + t * 16 + lm][lk]);
    }
#pragma unroll
    for (int mt = 0; mt < 4; mt++)
#pragma unroll
      for (int nt = 0; nt < 4; nt++)
        acc[mt][nt] = __builtin_amdgcn_mfma_f32_16x16x32_bf16(af[mt], bfr[nt], acc[mt][nt], 0, 0, 0);
  }
  // epilogue: C/D layout col=lane&15, row=(lane>>4)*4+r
#pragma unroll
  for (int nt = 0; nt < 4; nt++) {
    int col = n0 + wn + nt * 16 + lm;
    float bv = bias[col];
#pragma unroll
    for (int mt = 0; mt < 4; mt++) {
#pragma unroll
      for (int r = 0; r < 4; r++) {
        int row = m0 + wm + mt * 16 + lq * 4 + r;
        float v = acc[mt][nt][r] + bv;
        if (RELU) v = fmaxf(v, 0.0f);
        if (OUT_BF16) ((unsigned short*)Cout)[(size_t)row * N + col] = f2bf(v);
        else          ((float*)Cout)[(size_t)row * N + col] = v;
      }
    }
  }
}

// ------------- attention v4: R4 shape (128 q/block, 32 q/wave, 4 blocks/CU) -------------
// + register prefetch of next K/V tile (loads overlap compute)
// + exp2 path (log2e folded into Q; bare v_exp_f32 per element)
// S^T = K*Q^T formulation; lower clip dropped (negligible vs rowsum); shift cancels.
// Rowsum via MFMA vs all-ones; per-wave Ps roundtrip (lgkm wait only, no barrier).
// LDS XOR swizzle phys_col = col ^ ((row&7)*8); 32 KB LDS.
__global__ __launch_bounds__(256, 4) void attn_kernel(
    const unsigned short* __restrict__ QKV,   // [8192][3072]: q|k|v
    const unsigned short* __restrict__ Vt_g,  // [64 bh][64 dh][2048 kv]
    unsigned short* __restrict__ ctx) {       // [8192][1024]
  __shared__ __align__(16) unsigned short Ks[64 * 64];       // [kv][dh] swizzled
  __shared__ __align__(16) unsigned short Vs[64 * 64];       // [dh][kv] swizzled
  __shared__ __align__(16) unsigned short Ps[4 * 32 * 64];   // per-wave [q][kv] swizzled
  const int bh = blockIdx.x, b = bh >> 4, h = bh & 15;
  const int q0 = blockIdx.y * 128;
  const int tid = threadIdx.x, wave = tid >> 6, lane = tid & 63;
  const int lm = lane & 15, lq = lane >> 4;
  const int srow = tid >> 3, scol = (tid & 7) * 8;           // srow 0..31
  const int rot = (lm & 7) * 8;

  // Q fragments (wave's 32 q-rows, 2 n-tiles x 2 k-slabs), stay in regs
  short8 qf[2][2];
#pragma unroll
  for (int ntq = 0; ntq < 2; ntq++) {
    const unsigned short* qp =
        QKV + (size_t)(b * SEQ + q0 + wave * 32 + ntq * 16 + lm) * 3072 + h * DH;
#pragma unroll
    for (int sl = 0; sl < 2; sl++) qf[ntq][sl] = *(const short8*)(qp + sl * 32 + lq * 8);
  }
  const short8 ones = {0x3F80, 0x3F80, 0x3F80, 0x3F80, 0x3F80, 0x3F80, 0x3F80, 0x3F80};
  f32x4 oacc[2][4] = {};
  f32x4 lsum[2] = {};

  const int sdst = srow * 64 + (scol ^ ((srow & 7) * 8));   // rows 0..31; +2048 for 32..63
  const unsigned short* kg = QKV + (size_t)(b * SEQ) * 3072 + D_MODEL + h * DH + scol;
  const unsigned short* vg = Vt_g + (size_t)(bh * DH + srow) * SEQ + scol;

  // prefetch tile 0
  uint4 kr0 = *(const uint4*)(kg + (size_t)srow * 3072);
  uint4 kr1 = *(const uint4*)(kg + (size_t)(srow + 32) * 3072);
  uint4 vr0 = *(const uint4*)(vg);
  uint4 vr1 = *(const uint4*)(vg + 32 * SEQ);

  for (int it = 0; it < SEQ / 64; it++) {
    *(uint4*)(Ks + sdst)        = kr0;
    *(uint4*)(Ks + sdst + 2048) = kr1;
    *(uint4*)(Vs + sdst)        = vr0;
    *(uint4*)(Vs + sdst + 2048) = vr1;
    __syncthreads();
    if (it + 1 < SEQ / 64) {   // prefetch next tile; overlaps the whole compute phase
      const int kvn = (it + 1) * 64;
      kr0 = *(const uint4*)(kg + (size_t)(kvn + srow) * 3072);
      kr1 = *(const uint4*)(kg + (size_t)(kvn + srow + 32) * 3072);
      vr0 = *(const uint4*)(vg + kvn);
      vr1 = *(const uint4*)(vg + 32 * SEQ + kvn);
    }

    // S^T = K * Q^T ; p = exp2(min(s',CLIP2)); truncation-pack to per-wave Ps
#pragma unroll
    for (int mt = 0; mt < 4; mt++) {
      const unsigned short* krow = Ks + (mt * 16 + lm) * 64;
      short8 kf0 = *(const short8*)(krow + ((lq * 8) ^ rot));
      short8 kf1 = *(const short8*)(krow + ((32 + lq * 8) ^ rot));
#pragma unroll
      for (int ntq = 0; ntq < 2; ntq++) {
        f32x4 sa = {0.f, 0.f, 0.f, 0.f};
        sa = __builtin_amdgcn_mfma_f32_16x16x32_bf16(kf0, qf[ntq][0], sa, 0, 0, 0);
        sa = __builtin_amdgcn_mfma_f32_16x16x32_bf16(kf1, qf[ntq][1], sa, 0, 0, 0);
        float p0 = EXP2(fminf(sa[0], CLIP2));
        float p1 = EXP2(fminf(sa[1], CLIP2));
        float p2 = EXP2(fminf(sa[2], CLIP2));
        float p3 = EXP2(fminf(sa[3], CLIP2));
        uint2 d;
        d.x = pack_trunc(p0, p1);
        d.y = pack_trunc(p2, p3);
        *(uint2*)(Ps + wave * 2048 + (ntq * 16 + lm) * 64 + ((mt * 16 + lq * 4) ^ rot)) = d;
      }
    }
    // wave-local LDS RAW: wait lgkmcnt(0) only (vmcnt=63, expcnt=7 -> 0xC07F)
    __builtin_amdgcn_s_waitcnt(0xC07F);
    short8 pf[2][2];
#pragma unroll
    for (int mq = 0; mq < 2; mq++)
#pragma unroll
      for (int sl = 0; sl < 2; sl++)
        pf[mq][sl] = *(const short8*)(Ps + wave * 2048 + (mq * 16 + lm) * 64 + ((sl * 32 + lq * 8) ^ rot));
#pragma unroll
    for (int nt = 0; nt < 4; nt++) {
      const unsigned short* vrow = Vs + (nt * 16 + lm) * 64;
      short8 vf0 = *(const short8*)(vrow + ((lq * 8) ^ rot));
      short8 vf1 = *(const short8*)(vrow + ((32 + lq * 8) ^ rot));
#pragma unroll
      for (int mq = 0; mq < 2; mq++) {
        oacc[mq][nt] = __builtin_amdgcn_mfma_f32_16x16x32_bf16(pf[mq][0], vf0, oacc[mq][nt], 0, 0, 0);
        oacc[mq][nt] = __builtin_amdgcn_mfma_f32_16x16x32_bf16(pf[mq][1], vf1, oacc[mq][nt], 0, 0, 0);
      }
    }
#pragma unroll
    for (int mq = 0; mq < 2; mq++) {
      lsum[mq] = __builtin_amdgcn_mfma_f32_16x16x32_bf16(pf[mq][0], ones, lsum[mq], 0, 0, 0);
      lsum[mq] = __builtin_amdgcn_mfma_f32_16x16x32_bf16(pf[mq][1], ones, lsum[mq], 0, 0, 0);
    }
    __syncthreads();   // all waves done reading Ks/Vs before next staging write
  }

#pragma unroll
  for (int mq = 0; mq < 2; mq++) {
    float linv[4];
#pragma unroll
    for (int r = 0; r < 4; r++) linv[r] = 1.0f / lsum[mq][r];
    const size_t rowbase =
        (size_t)(b * SEQ + q0 + wave * 32 + mq * 16 + lq * 4) * D_MODEL + h * DH;
#pragma unroll
    for (int nt = 0; nt < 4; nt++) {
#pragma unroll
      for (int r = 0; r < 4; r++) {
        ctx[rowbase + (size_t)r * D_MODEL + nt * 16 + lm] = f2bf(oacc[mq][nt][r] * linv[r]);
      }
    }
  }
}

// ------------- residual + layernorm (one block per row of 1024) -------------
template<int B_BF16, int WRITE_BF16>
__global__ void ln_kernel(const float* __restrict__ A, const void* __restrict__ Bv,
                          const float* __restrict__ gamma, const float* __restrict__ beta,
                          float* __restrict__ outf, unsigned short* __restrict__ outb) {
  const int row = blockIdx.x;
  const int tid = threadIdx.x;
  const size_t base = (size_t)row * D_MODEL + tid * 4;
  float4 xa = *(const float4*)(A + base);
  float4 xb;
  if (B_BF16) {
    ushort4 u = *(const ushort4*)((const unsigned short*)Bv + base);
    xb.x = bf2f(u.x); xb.y = bf2f(u.y); xb.z = bf2f(u.z); xb.w = bf2f(u.w);
  } else {
    xb = *(const float4*)((const float*)Bv + base);
  }
  float v0 = xa.x + xb.x, v1 = xa.y + xb.y, v2 = xa.z + xb.z, v3 = xa.w + xb.w;
  float s = v0 + v1 + v2 + v3;
  float sq = v0 * v0 + v1 * v1 + v2 * v2 + v3 * v3;
#pragma unroll
  for (int off = 1; off < 64; off <<= 1) {
    s  += __shfl_xor(s, off);
    sq += __shfl_xor(sq, off);
  }
  __shared__ float red[8];
  int wave = tid >> 6;
  if ((tid & 63) == 0) { red[wave * 2] = s; red[wave * 2 + 1] = sq; }
  __syncthreads();
  s  = red[0] + red[2] + red[4] + red[6];
  sq = red[1] + red[3] + red[5] + red[7];
  float mean = s * (1.0f / D_MODEL);
  float var = sq * (1.0f / D_MODEL) - mean * mean;
  float inv = rsqrtf(var + 1e-8f);
  float4 g  = *(const float4*)(gamma + tid * 4);
  float4 be = *(const float4*)(beta + tid * 4);
  float o0 = (v0 - mean) * inv * g.x + be.x;
  float o1 = (v1 - mean) * inv * g.y + be.y;
  float o2 = (v2 - mean) * inv * g.z + be.z;
  float o3 = (v3 - mean) * inv * g.w + be.w;
  float4 of; of.x = o0; of.y = o1; of.z = o2; of.w = o3;
  *(float4*)(outf + base) = of;
  if (WRITE_BF16) {
    ushort4 ub; ub.x = f2bf(o0); ub.y = f2bf(o1); ub.z = f2bf(o2); ub.w = f2bf(o3);
    *(ushort4*)(outb + base) = ub;
  }
}

extern "C" void kernel_launch(void* const* d_in, const int* in_sizes, int n_in,
                              void* d_out, int out_size, void* d_ws, size_t ws_size,
                              hipStream_t stream) {
  const float* x     = (const float*)d_in[0];
  const float* wq    = (const float*)d_in[1];
  const float* bq    = (const float*)d_in[2];
  const float* wk    = (const float*)d_in[3];
  const float* bk    = (const float*)d_in[4];
  const float* wv    = (const float*)d_in[5];
  const float* bv    = (const float*)d_in[6];
  const float* wo    = (const float*)d_in[7];
  const float* bo    = (const float*)d_in[8];
  const float* w1    = (const float*)d_in[9];
  const float* b1    = (const float*)d_in[10];
  const float* w2    = (const float*)d_in[11];
  const float* b2    = (const float*)d_in[12];
  const float* gamma = (const float*)d_in[13];
  const float* beta  = (const float*)d_in[14];

  char* ws = (char*)d_ws;
  const size_t MB = 1ull << 20;
  // buffer plan (aliasing over dead buffers):
  unsigned short* xb      = (unsigned short*)(ws + 0 * MB);    // 16 MB (dead after QKV gemm)
  unsigned short* out1b   = (unsigned short*)(ws + 0 * MB);    //   reuse xb slot after LN1
  unsigned short* wqkvT   = (unsigned short*)(ws + 16 * MB);   // 6 MB  [3072][1024]
  unsigned short* woT     = (unsigned short*)(ws + 22 * MB);   // 2 MB
  unsigned short* w1T     = (unsigned short*)(ws + 24 * MB);   // 8 MB
  unsigned short* w2T     = (unsigned short*)(ws + 32 * MB);   // 8 MB
  float*          bqkv    = (float*)(ws + 40 * MB);            // 12 KB (1 MB slot)
  unsigned short* qkvb    = (unsigned short*)(ws + 41 * MB);   // 48 MB [8192][3072] (dead after attn)
  unsigned short* attnoutb= (unsigned short*)(ws + 41 * MB);   //   16 MB bf16, reuse after attn
  unsigned short* h1      = (unsigned short*)(ws + 41 * MB);   //   64 MB, reuse after LN1 (41..105)
  unsigned short* Vt_g    = (unsigned short*)(ws + 89 * MB);   // 16 MB (dead after attn)
  unsigned short* ctx     = (unsigned short*)(ws + 105 * MB);  // 16 MB (dead after out-proj)
  unsigned short* ffnb    = (unsigned short*)(ws + 105 * MB);  //   16 MB, reuse
  float*          out1f   = (float*)(ws + 121 * MB);           // 32 MB (live till end)

  // preprocessing (3 launches total)
  cast_kernel<<<(MTOT * D_MODEL / 4 + 255) / 256, 256, 0, stream>>>(x, xb, MTOT * D_MODEL / 4);
  transpose_weights_kernel<<<dim3(128, 128, 6), 256, 0, stream>>>(
      wq, wk, wv, wo, w1, w2, wqkvT, woT, w1T, w2T);
  bias_concat_kernel<<<12, 256, 0, stream>>>(bq, bk, bv, bqkv);

  // fused QKV projection: [8192][3072]  (1D grid, XCD-swizzled)
  gemm_bt_kernel<0, 1><<<(3072 / 128) * (MTOT / 128), 256, 0, stream>>>(
      xb, wqkvT, bqkv, qkvb, MTOT, 3072, D_MODEL);
  // V -> Vt_g[bh][dh][kv]
  transpose_v_kernel<<<dim3(SEQ / 32, DH / 32, BATCH * NHEAD), 256, 0, stream>>>(qkvb, Vt_g);
  // attention: 128 q/block, 32 q/wave; grid.x = bh (q-blocks of one bh share an XCD's L2)
  attn_kernel<<<dim3(BATCH * NHEAD, SEQ / 128), 256, 0, stream>>>(qkvb, Vt_g, ctx);

  gemm_bt_kernel<0, 1><<<(D_MODEL / 128) * (MTOT / 128), 256, 0, stream>>>(
      ctx, woT, bo, attnoutb, MTOT, D_MODEL, D_MODEL);
  ln_kernel<1, 1><<<MTOT, 256, 0, stream>>>(x, attnoutb, gamma, beta, out1f, out1b);
  gemm_bt_kernel<1, 1><<<(DFF / 128) * (MTOT / 128), 256, 0, stream>>>(
      out1b, w1T, b1, h1, MTOT, DFF, D_MODEL);
  gemm_bt_kernel<0, 1><<<(D_MODEL / 128) * (MTOT / 128), 256, 0, stream>>>(
      h1, w2T, b2, ffnb, MTOT, D_MODEL, DFF);
  ln_kernel<1, 0><<<MTOT, 256, 0, stream>>>(out1f, ffnb, gamma, beta, (float*)d_out, nullptr);
}

// Round 7
// 539.975 us; speedup vs baseline: 1.0519x; 1.0519x over previous
//
#include <hip/hip_runtime.h>
#include <stdint.h>

#define D_MODEL 1024
#define NHEAD 16
#define DH 64
#define DFF 4096
#define BATCH 4
#define SEQ 2048
#define MTOT (BATCH*SEQ)   // 8192 rows total

// Q pre-scale folds 1/sqrt(Dh) AND log2(e) so softmax is a bare v_exp_f32 (exp2):
//   s' = s * log2e;  p = exp2(min(s', 10*log2e)) = exp(min(s,10))
#define QSCALE 0.18033688011112043f   // 0.125 * log2(e)
#define CLIP2  14.426950408889634f    // 10 * log2(e)

typedef short short8 __attribute__((ext_vector_type(8)));
typedef float f32x4 __attribute__((ext_vector_type(4)));
typedef unsigned int uint;

__device__ inline unsigned short f2bf(float f) {
  union { float f; unsigned u; } v; v.f = f;
  unsigned r = v.u + 0x7fffu + ((v.u >> 16) & 1u);
  return (unsigned short)(r >> 16);
}
__device__ inline float bf2f(unsigned short b) {
  union { unsigned u; float f; } v; v.u = ((unsigned)b) << 16;
  return v.f;
}
// truncation-pack two floats to bf16 pair in one dword: [lo | hi<<16]
__device__ inline unsigned pack_trunc(float lo, float hi) {
  union { float f; unsigned u; } a, b; a.f = lo; b.f = hi;
  return __builtin_amdgcn_perm(b.u, a.u, 0x07060302u);
}
// async 16B global -> LDS (wave-uniform base + lane*16 contract)
__device__ __forceinline__ void async16(const unsigned short* g, unsigned short* l) {
  __builtin_amdgcn_global_load_lds(
      (const __attribute__((address_space(1))) unsigned int*)g,
      (__attribute__((address_space(3))) unsigned int*)l, 16, 0, 0);
}

// ---------------- cast x -> bf16 ----------------
__global__ void cast_kernel(const float* __restrict__ in, unsigned short* __restrict__ out, int n4) {
  int i = blockIdx.x * blockDim.x + threadIdx.x;
  if (i < n4) {
    float4 v = ((const float4*)in)[i];
    ushort4 o;
    o.x = f2bf(v.x); o.y = f2bf(v.y); o.z = f2bf(v.z); o.w = f2bf(v.w);
    ((ushort4*)out)[i] = o;
  }
}

// ------------- ALL weight transposes, ONE launch, EXACT flat grid (12288 blocks) -------------
// tiles: [0,4096): wq|wk|wv|wo (1024 each); [4096,8192): w1; [8192,12288): w2
__global__ void transpose_weights_kernel(
    const float* __restrict__ wq, const float* __restrict__ wk,
    const float* __restrict__ wv, const float* __restrict__ wo,
    const float* __restrict__ w1, const float* __restrict__ w2,
    unsigned short* __restrict__ wqkvT, unsigned short* __restrict__ woT,
    unsigned short* __restrict__ w1T, unsigned short* __restrict__ w2T) {
  __shared__ unsigned short tile[32][33];
  const int id = blockIdx.x;
  const float* in; unsigned short* out; int K, N, n0, k0; float scale = 1.0f;
  if (id < 4096) {
    const int wi = id >> 10, t = id & 1023;
    switch (wi) {
      case 0:  in = wq; out = wqkvT;           scale = QSCALE; break;
      case 1:  in = wk; out = wqkvT + 1048576; break;
      case 2:  in = wv; out = wqkvT + 2097152; break;
      default: in = wo; out = woT;             break;
    }
    K = 1024; N = 1024; n0 = (t & 31) * 32; k0 = (t >> 5) * 32;
  } else if (id < 8192) {
    const int t = id - 4096;
    in = w1; out = w1T; K = 1024; N = 4096; n0 = (t & 127) * 32; k0 = (t >> 7) * 32;
  } else {
    const int t = id - 8192;
    in = w2; out = w2T; K = 4096; N = 1024; n0 = (t & 31) * 32; k0 = (t >> 5) * 32;
  }
  const int tx = threadIdx.x & 31, ty = threadIdx.x >> 5;  // 32 x 8
#pragma unroll
  for (int j = 0; j < 32; j += 8)
    tile[ty + j][tx] = f2bf(in[(size_t)(k0 + ty + j) * N + n0 + tx] * scale);
  __syncthreads();
#pragma unroll
  for (int j = 0; j < 32; j += 8)
    out[(size_t)(n0 + ty + j) * K + k0 + tx] = tile[tx][ty + j];
}

// ------------- concat + scale biases into [3072] -------------
__global__ void bias_concat_kernel(const float* __restrict__ bq, const float* __restrict__ bk,
                                   const float* __restrict__ bv, float* __restrict__ o) {
  int i = blockIdx.x * 256 + threadIdx.x;
  if (i < 3 * D_MODEL) {
    float v = (i < D_MODEL) ? bq[i] * QSCALE
            : (i < 2 * D_MODEL) ? bk[i - D_MODEL] : bv[i - 2 * D_MODEL];
    o[i] = v;
  }
}

// ------------- transpose V (from qkv cols 2048..3071) into Vt_g[bh][dh][kv] -------------
__global__ void transpose_v_kernel(const unsigned short* __restrict__ QKV,
                                   unsigned short* __restrict__ Vt) {
  __shared__ unsigned short tile[32][33];
  int bh = blockIdx.z, b = bh >> 4, h = bh & 15;
  int kv0 = blockIdx.x * 32, dh0 = blockIdx.y * 32;
  int tx = threadIdx.x & 31, ty = threadIdx.x >> 5;  // 32 x 8
#pragma unroll
  for (int j = 0; j < 32; j += 8)
    tile[ty + j][tx] = QKV[(size_t)(b * SEQ + kv0 + ty + j) * 3072 + 2048 + h * DH + dh0 + tx];
  __syncthreads();
#pragma unroll
  for (int j = 0; j < 32; j += 8)
    Vt[(size_t)(bh * DH + dh0 + ty + j) * SEQ + kv0 + tx] = tile[tx][ty + j];
}

// ------------- GEMM: C[M][N] = A[M][K] * Bt[N][K]^T (+bias) -------------
// 1D grid, XCD-compact swizzle (xcd = blockIdx.x&7, 8 m-tile band, n-fast).
// KSPLIT=2: doubles the grid; each block computes half of K and writes a bf16 partial
// at Cout + kh*M*N (partials summed in the following LN kernel). Raises blocks/CU
// 2->4 for the grid-limited K=4096 GEMM (FFN2) -> more barrier-drain overlap.
template<int RELU, int OUT_BF16, int KSPLIT, int BIAS>
__global__ __launch_bounds__(256, 4) void gemm_bt_kernel(
    const unsigned short* __restrict__ A,
    const unsigned short* __restrict__ Bt,
    const float* __restrict__ bias,
    void* __restrict__ Cout,
    int M, int N, int K) {
  __shared__ __align__(16) unsigned short As[128][32];
  __shared__ __align__(16) unsigned short Bs[128][32];
  const int GX = N >> 7;                    // n-tiles
  const int xcd = blockIdx.x & 7;
  int li = blockIdx.x >> 3;
  int kh = 0;
  if (KSPLIT == 2) { kh = li & 1; li >>= 1; }
  const int im = xcd * 8 + li / GX;         // m-tile (8 per XCD band, M=8192 always)
  const int in_ = li % GX;                  // n-tile, fast-varying within band
  const int m0 = im * 128, n0 = in_ * 128;
  const int tid = threadIdx.x;
  const int wave = tid >> 6, lane = tid & 63;
  const int wm = (wave >> 1) * 64, wn = (wave & 1) * 64;
  const int lm = lane & 15, lq = lane >> 4, lk = (lane >> 4) * 8;
  const int sr = tid >> 2;          // staging row 0..63 (+64 on 2nd round)
  const int sc = (tid & 3) * 8;     // staging col {0,8,16,24}
  f32x4 acc[4][4] = {};

  const int kbeg = (KSPLIT == 2) ? kh * (K >> 1) : 0;
  const int kend = (KSPLIT == 2) ? kbeg + (K >> 1) : K;
  for (int k0 = kbeg; k0 < kend; k0 += 32) {
    __syncthreads();
#pragma unroll
    for (int s = 0; s < 2; s++) {
      int row = sr + s * 64;
      async16(A  + (size_t)(m0 + row) * K + k0 + sc, &As[0][0] + row * 32 + sc);
      async16(Bt + (size_t)(n0 + row) * K + k0 + sc, &Bs[0][0] + row * 32 + sc);
    }
    __syncthreads();
    short8 af[4], bfr[4];
#pragma unroll
    for (int t = 0; t < 4; t++) {
      af[t]  = *(const short8*)(&As[wm + t * 16 + lm][lk]);
      bfr[t] = *(const short8*)(&Bs[wn + t * 16 + lm][lk]);
    }
#pragma unroll
    for (int mt = 0; mt < 4; mt++)
#pragma unroll
      for (int nt = 0; nt < 4; nt++)
        acc[mt][nt] = __builtin_amdgcn_mfma_f32_16x16x32_bf16(af[mt], bfr[nt], acc[mt][nt], 0, 0, 0);
  }
  // epilogue: C/D layout col=lane&15, row=(lane>>4)*4+r
  unsigned short* Cb = (unsigned short*)Cout + (KSPLIT == 2 ? (size_t)kh * M * N : 0);
#pragma unroll
  for (int nt = 0; nt < 4; nt++) {
    int col = n0 + wn + nt * 16 + lm;
    float bv = BIAS ? bias[col] : 0.0f;
#pragma unroll
    for (int mt = 0; mt < 4; mt++) {
#pragma unroll
      for (int r = 0; r < 4; r++) {
        int row = m0 + wm + mt * 16 + lq * 4 + r;
        float v = acc[mt][nt][r] + bv;
        if (RELU) v = fmaxf(v, 0.0f);
        if (OUT_BF16) Cb[(size_t)row * N + col] = f2bf(v);
        else          ((float*)Cout)[(size_t)row * N + col] = v;
      }
    }
  }
}

// ------------- attention: 128 q/block, 32 q/wave, 4 blocks/CU, reg-prefetch K/V -------------
// S^T = K*Q^T; p = exp2(min(s',CLIP2)) via native v_exp_f32; lower clip dropped
// (negligible vs rowsum); shift cancels in normalization. Rowsum via MFMA vs all-ones.
// Per-wave Ps roundtrip (lgkm wait only). LDS XOR swizzle phys_col = col ^ ((row&7)*8).
__global__ __launch_bounds__(256, 4) void attn_kernel(
    const unsigned short* __restrict__ QKV,   // [8192][3072]: q|k|v
    const unsigned short* __restrict__ Vt_g,  // [64 bh][64 dh][2048 kv]
    unsigned short* __restrict__ ctx) {       // [8192][1024]
  __shared__ __align__(16) unsigned short Ks[64 * 64];       // [kv][dh] swizzled
  __shared__ __align__(16) unsigned short Vs[64 * 64];       // [dh][kv] swizzled
  __shared__ __align__(16) unsigned short Ps[4 * 32 * 64];   // per-wave [q][kv] swizzled
  const int bh = blockIdx.x, b = bh >> 4, h = bh & 15;
  const int q0 = blockIdx.y * 128;
  const int tid = threadIdx.x, wave = tid >> 6, lane = tid & 63;
  const int lm = lane & 15, lq = lane >> 4;
  const int srow = tid >> 3, scol = (tid & 7) * 8;           // srow 0..31
  const int rot = (lm & 7) * 8;

  short8 qf[2][2];
#pragma unroll
  for (int ntq = 0; ntq < 2; ntq++) {
    const unsigned short* qp =
        QKV + (size_t)(b * SEQ + q0 + wave * 32 + ntq * 16 + lm) * 3072 + h * DH;
#pragma unroll
    for (int sl = 0; sl < 2; sl++) qf[ntq][sl] = *(const short8*)(qp + sl * 32 + lq * 8);
  }
  const short8 ones = {0x3F80, 0x3F80, 0x3F80, 0x3F80, 0x3F80, 0x3F80, 0x3F80, 0x3F80};
  f32x4 oacc[2][4] = {};
  f32x4 lsum[2] = {};

  const int sdst = srow * 64 + (scol ^ ((srow & 7) * 8));   // rows 0..31; +2048 for 32..63
  const unsigned short* kg = QKV + (size_t)(b * SEQ) * 3072 + D_MODEL + h * DH + scol;
  const unsigned short* vg = Vt_g + (size_t)(bh * DH + srow) * SEQ + scol;

  // prefetch tile 0
  uint4 kr0 = *(const uint4*)(kg + (size_t)srow * 3072);
  uint4 kr1 = *(const uint4*)(kg + (size_t)(srow + 32) * 3072);
  uint4 vr0 = *(const uint4*)(vg);
  uint4 vr1 = *(const uint4*)(vg + 32 * SEQ);

  for (int it = 0; it < SEQ / 64; it++) {
    *(uint4*)(Ks + sdst)        = kr0;
    *(uint4*)(Ks + sdst + 2048) = kr1;
    *(uint4*)(Vs + sdst)        = vr0;
    *(uint4*)(Vs + sdst + 2048) = vr1;
    __syncthreads();
    if (it + 1 < SEQ / 64) {   // prefetch next tile; overlaps the whole compute phase
      const int kvn = (it + 1) * 64;
      kr0 = *(const uint4*)(kg + (size_t)(kvn + srow) * 3072);
      kr1 = *(const uint4*)(kg + (size_t)(kvn + srow + 32) * 3072);
      vr0 = *(const uint4*)(vg + kvn);
      vr1 = *(const uint4*)(vg + 32 * SEQ + kvn);
    }

    // S^T = K * Q^T ; p = exp2(min(s',CLIP2)); truncation-pack to per-wave Ps
#pragma unroll
    for (int mt = 0; mt < 4; mt++) {
      const unsigned short* krow = Ks + (mt * 16 + lm) * 64;
      short8 kf0 = *(const short8*)(krow + ((lq * 8) ^ rot));
      short8 kf1 = *(const short8*)(krow + ((32 + lq * 8) ^ rot));
#pragma unroll
      for (int ntq = 0; ntq < 2; ntq++) {
        f32x4 sa = {0.f, 0.f, 0.f, 0.f};
        sa = __builtin_amdgcn_mfma_f32_16x16x32_bf16(kf0, qf[ntq][0], sa, 0, 0, 0);
        sa = __builtin_amdgcn_mfma_f32_16x16x32_bf16(kf1, qf[ntq][1], sa, 0, 0, 0);
        float p0 = exp2f(fminf(sa[0], CLIP2));
        float p1 = exp2f(fminf(sa[1], CLIP2));
        float p2 = exp2f(fminf(sa[2], CLIP2));
        float p3 = exp2f(fminf(sa[3], CLIP2));
        uint2 d;
        d.x = pack_trunc(p0, p1);
        d.y = pack_trunc(p2, p3);
        *(uint2*)(Ps + wave * 2048 + (ntq * 16 + lm) * 64 + ((mt * 16 + lq * 4) ^ rot)) = d;
      }
    }
    // wave-local LDS RAW: wait lgkmcnt(0) only (vmcnt=63, expcnt=7 -> 0xC07F)
    __builtin_amdgcn_s_waitcnt(0xC07F);
    short8 pf[2][2];
#pragma unroll
    for (int mq = 0; mq < 2; mq++)
#pragma unroll
      for (int sl = 0; sl < 2; sl++)
        pf[mq][sl] = *(const short8*)(Ps + wave * 2048 + (mq * 16 + lm) * 64 + ((sl * 32 + lq * 8) ^ rot));
#pragma unroll
    for (int nt = 0; nt < 4; nt++) {
      const unsigned short* vrow = Vs + (nt * 16 + lm) * 64;
      short8 vf0 = *(const short8*)(vrow + ((lq * 8) ^ rot));
      short8 vf1 = *(const short8*)(vrow + ((32 + lq * 8) ^ rot));
#pragma unroll
      for (int mq = 0; mq < 2; mq++) {
        oacc[mq][nt] = __builtin_amdgcn_mfma_f32_16x16x32_bf16(pf[mq][0], vf0, oacc[mq][nt], 0, 0, 0);
        oacc[mq][nt] = __builtin_amdgcn_mfma_f32_16x16x32_bf16(pf[mq][1], vf1, oacc[mq][nt], 0, 0, 0);
      }
    }
#pragma unroll
    for (int mq = 0; mq < 2; mq++) {
      lsum[mq] = __builtin_amdgcn_mfma_f32_16x16x32_bf16(pf[mq][0], ones, lsum[mq], 0, 0, 0);
      lsum[mq] = __builtin_amdgcn_mfma_f32_16x16x32_bf16(pf[mq][1], ones, lsum[mq], 0, 0, 0);
    }
    __syncthreads();   // all waves done reading Ks/Vs before next staging write
  }

#pragma unroll
  for (int mq = 0; mq < 2; mq++) {
    float linv[4];
#pragma unroll
    for (int r = 0; r < 4; r++) linv[r] = 1.0f / lsum[mq][r];
    const size_t rowbase =
        (size_t)(b * SEQ + q0 + wave * 32 + mq * 16 + lq * 4) * D_MODEL + h * DH;
#pragma unroll
    for (int nt = 0; nt < 4; nt++) {
#pragma unroll
      for (int r = 0; r < 4; r++) {
        ctx[rowbase + (size_t)r * D_MODEL + nt * 16 + lm] = f2bf(oacc[mq][nt][r] * linv[r]);
      }
    }
  }
}

// ------------- residual + layernorm -------------
// THREE=1: out = LN(A + bf16(B1) + bf16(B2) + cbias)  (split-K partial merge + bias)
template<int B_BF16, int WRITE_BF16, int THREE>
__global__ void ln_kernel(const float* __restrict__ A, const void* __restrict__ Bv,
                          const void* __restrict__ B2v, const float* __restrict__ cbias,
                          const float* __restrict__ gamma, const float* __restrict__ beta,
                          float* __restrict__ outf, unsigned short* __restrict__ outb) {
  const int row = blockIdx.x;
  const int tid = threadIdx.x;
  const size_t base = (size_t)row * D_MODEL + tid * 4;
  float4 xa = *(const float4*)(A + base);
  float4 xb;
  if (B_BF16) {
    ushort4 u = *(const ushort4*)((const unsigned short*)Bv + base);
    xb.x = bf2f(u.x); xb.y = bf2f(u.y); xb.z = bf2f(u.z); xb.w = bf2f(u.w);
  } else {
    xb = *(const float4*)((const float*)Bv + base);
  }
  if (THREE) {
    ushort4 u2 = *(const ushort4*)((const unsigned short*)B2v + base);
    float4 cb = *(const float4*)(cbias + tid * 4);
    xb.x += bf2f(u2.x) + cb.x; xb.y += bf2f(u2.y) + cb.y;
    xb.z += bf2f(u2.z) + cb.z; xb.w += bf2f(u2.w) + cb.w;
  }
  float v0 = xa.x + xb.x, v1 = xa.y + xb.y, v2 = xa.z + xb.z, v3 = xa.w + xb.w;
  float s = v0 + v1 + v2 + v3;
  float sq = v0 * v0 + v1 * v1 + v2 * v2 + v3 * v3;
#pragma unroll
  for (int off = 1; off < 64; off <<= 1) {
    s  += __shfl_xor(s, off);
    sq += __shfl_xor(sq, off);
  }
  __shared__ float red[8];
  int wave = tid >> 6;
  if ((tid & 63) == 0) { red[wave * 2] = s; red[wave * 2 + 1] = sq; }
  __syncthreads();
  s  = red[0] + red[2] + red[4] + red[6];
  sq = red[1] + red[3] + red[5] + red[7];
  float mean = s * (1.0f / D_MODEL);
  float var = sq * (1.0f / D_MODEL) - mean * mean;
  float inv = rsqrtf(var + 1e-8f);
  float4 g  = *(const float4*)(gamma + tid * 4);
  float4 be = *(const float4*)(beta + tid * 4);
  float o0 = (v0 - mean) * inv * g.x + be.x;
  float o1 = (v1 - mean) * inv * g.y + be.y;
  float o2 = (v2 - mean) * inv * g.z + be.z;
  float o3 = (v3 - mean) * inv * g.w + be.w;
  float4 of; of.x = o0; of.y = o1; of.z = o2; of.w = o3;
  *(float4*)(outf + base) = of;
  if (WRITE_BF16) {
    ushort4 ub; ub.x = f2bf(o0); ub.y = f2bf(o1); ub.z = f2bf(o2); ub.w = f2bf(o3);
    *(ushort4*)(outb + base) = ub;
  }
}

extern "C" void kernel_launch(void* const* d_in, const int* in_sizes, int n_in,
                              void* d_out, int out_size, void* d_ws, size_t ws_size,
                              hipStream_t stream) {
  const float* x     = (const float*)d_in[0];
  const float* wq    = (const float*)d_in[1];
  const float* bq    = (const float*)d_in[2];
  const float* wk    = (const float*)d_in[3];
  const float* bk    = (const float*)d_in[4];
  const float* wv    = (const float*)d_in[5];
  const float* bv    = (const float*)d_in[6];
  const float* wo    = (const float*)d_in[7];
  const float* bo    = (const float*)d_in[8];
  const float* w1    = (const float*)d_in[9];
  const float* b1    = (const float*)d_in[10];
  const float* w2    = (const float*)d_in[11];
  const float* b2    = (const float*)d_in[12];
  const float* gamma = (const float*)d_in[13];
  const float* beta  = (const float*)d_in[14];

  char* ws = (char*)d_ws;
  const size_t MB = 1ull << 20;
  // buffer plan — phase-aliased (stream order guarantees no overlap-in-time):
  //   [0,16)   xb (cast->QKV)  /  out1b (LN1->FFN1)
  //   [0,32)   ffn2 partials (FFN2->LN2; overwrites dead xb/out1b AND dead wqkvT/woT/w1T)
  //   [16,22)  wqkvT  [22,24) woT  [24,32) w1T  [32,40) w2T  [40,41) bqkv
  //   [41,89)  qkvb (QKV->attn) / attnoutb@41 (outproj->LN1) / h1@[41,105) (FFN1->FFN2)
  //   [89,105) Vt_g (->attn)
  //   [105,121) ctx (attn->outproj)
  //   [121,153) out1f (LN1->LN2)
  unsigned short* xb      = (unsigned short*)(ws + 0 * MB);
  unsigned short* out1b   = (unsigned short*)(ws + 0 * MB);
  unsigned short* ffn2    = (unsigned short*)(ws + 0 * MB);    // 32 MB: two bf16 partials
  unsigned short* wqkvT   = (unsigned short*)(ws + 16 * MB);
  unsigned short* woT     = (unsigned short*)(ws + 22 * MB);
  unsigned short* w1T     = (unsigned short*)(ws + 24 * MB);
  unsigned short* w2T     = (unsigned short*)(ws + 32 * MB);
  float*          bqkv    = (float*)(ws + 40 * MB);
  unsigned short* qkvb    = (unsigned short*)(ws + 41 * MB);
  unsigned short* attnoutb= (unsigned short*)(ws + 41 * MB);
  unsigned short* h1      = (unsigned short*)(ws + 41 * MB);
  unsigned short* Vt_g    = (unsigned short*)(ws + 89 * MB);
  unsigned short* ctx     = (unsigned short*)(ws + 105 * MB);
  float*          out1f   = (float*)(ws + 121 * MB);

  // preprocessing (3 launches; transpose grid is exact: 12288 tiles)
  cast_kernel<<<(MTOT * D_MODEL / 4 + 255) / 256, 256, 0, stream>>>(x, xb, MTOT * D_MODEL / 4);
  transpose_weights_kernel<<<12288, 256, 0, stream>>>(
      wq, wk, wv, wo, w1, w2, wqkvT, woT, w1T, w2T);
  bias_concat_kernel<<<12, 256, 0, stream>>>(bq, bk, bv, bqkv);

  // fused QKV projection: [8192][3072]  (1D grid, XCD-swizzled)
  gemm_bt_kernel<0, 1, 1, 1><<<(3072 / 128) * (MTOT / 128), 256, 0, stream>>>(
      xb, wqkvT, bqkv, qkvb, MTOT, 3072, D_MODEL);
  // V -> Vt_g[bh][dh][kv]
  transpose_v_kernel<<<dim3(SEQ / 32, DH / 32, BATCH * NHEAD), 256, 0, stream>>>(qkvb, Vt_g);
  // attention: 128 q/block, 32 q/wave; grid.x = bh (q-blocks of one bh share an XCD's L2)
  attn_kernel<<<dim3(BATCH * NHEAD, SEQ / 128), 256, 0, stream>>>(qkvb, Vt_g, ctx);

  gemm_bt_kernel<0, 1, 1, 1><<<(D_MODEL / 128) * (MTOT / 128), 256, 0, stream>>>(
      ctx, woT, bo, attnoutb, MTOT, D_MODEL, D_MODEL);
  ln_kernel<1, 1, 0><<<MTOT, 256, 0, stream>>>(
      x, attnoutb, nullptr, nullptr, gamma, beta, out1f, out1b);
  gemm_bt_kernel<1, 1, 1, 1><<<(DFF / 128) * (MTOT / 128), 256, 0, stream>>>(
      out1b, w1T, b1, h1, MTOT, DFF, D_MODEL);
  // FFN2 split-K=2: 1024 blocks, bf16 partials; bias b2 folded into LN2
  gemm_bt_kernel<0, 1, 2, 0><<<2 * (D_MODEL / 128) * (MTOT / 128), 256, 0, stream>>>(
      h1, w2T, nullptr, ffn2, MTOT, D_MODEL, DFF);
  ln_kernel<1, 0, 1><<<MTOT, 256, 0, stream>>>(
      out1f, ffn2, ffn2 + (size_t)MTOT * D_MODEL, b2, gamma, beta, (float*)d_out, nullptr);
}